// Round 1
// baseline (1116.869 us; speedup 1.0000x reference)
//
#include <hip/hip_runtime.h>
#include <math.h>

#define DINL __device__ __forceinline__

// ---------------- geometry ----------------
// image: [1536][48][72]
// conv1: -> [32][23][35]  (805 spatial)
// conv2: -> [64][11][17]  (187 spatial), stored as [n][sp][oc]
// conv3: -> [32][5][8]    (40 spatial) -> feat 1280, + rel_pos 3 -> 1283
// LTC: UNITS=48, ODE_UNFOLDS=6, S=48, B=32

static constexpr int O_OUT2 = 0;                         // [1536][187][64]
static constexpr int O_X    = O_OUT2 + 1536 * 187 * 64;  // [1536][1283]
static constexpr int O_WNUM = O_X + 1536 * 1283;         // [1536][48]
static constexpr int O_WDEN = O_WNUM + 1536 * 48;
static constexpr int O_SSIG = O_WDEN + 1536 * 48;        // [48][1283] transposed
static constexpr int O_SMU  = O_SSIG + 48 * 1283;
static constexpr int O_SW   = O_SMU + 48 * 1283;
static constexpr int O_SWE  = O_SW + 48 * 1283;
static constexpr int O_WM   = O_SWE + 48 * 1283;         // [48][48] w_syn*mask
static constexpr int O_WME  = O_WM + 48 * 48;            // [48][48] w_syn*mask*erev
static constexpr int O_W1T  = O_WME + 48 * 48;           // [32][9][64]: [c][k][oc]
static constexpr int O_W2T  = O_W1T + 32 * 9 * 64;       // [32][9][64]: [oc][k][c]

DINL float sigmoid_f(float z) {
  return __builtin_amdgcn_rcpf(1.f + __expf(-z));
}

// -------- pre: transpose sensory params to [j][i], fold mask & erev --------
__global__ void k_pre_sensory(const float* ssig, const float* smu, const float* sw,
                              const float* serev, const int* smask,
                              float* o_sig, float* o_mu, float* o_w, float* o_we) {
  int idx = blockIdx.x * 256 + threadIdx.x;
  if (idx >= 1283 * 48) return;
  int i = idx / 48, j = idx - i * 48;
  float m  = (float)smask[idx];
  float w  = sw[idx] * m;
  int o = j * 1283 + i;
  o_sig[o] = ssig[idx];
  o_mu[o]  = smu[idx];
  o_w[o]   = w;
  o_we[o]  = w * serev[idx];
}

// -------- pre: recurrent params, fold mask & erev (keep [i][j]) --------
__global__ void k_pre_rec(const float* w_syn, const float* erev, const int* mask,
                          float* o_wm, float* o_wme) {
  int idx = blockIdx.x * 256 + threadIdx.x;
  if (idx >= 48 * 48) return;
  float wm = w_syn[idx] * (float)mask[idx];
  o_wm[idx]  = wm;
  o_wme[idx] = wm * erev[idx];
}

// -------- pre: weight transposes for coalesced loads --------
__global__ void k_pre_w(const float* w1, const float* w2, float* w1t, float* w2t) {
  int idx = blockIdx.x * 256 + threadIdx.x;
  if (idx < 18432) {          // w1 [64][32][9] -> [c][k][oc]
    int oc = idx / 288;
    int rem = idx - oc * 288;
    int c = rem / 9, k = rem - c * 9;
    w1t[(c * 9 + k) * 64 + oc] = w1[idx];
  } else if (idx < 36864) {   // w2 [32][64][9] -> [oc][k][c]
    int i2 = idx - 18432;
    int oc = i2 / 576;
    int rem = i2 - oc * 576;
    int c = rem / 9, k = rem - c * 9;
    w2t[oc * 576 + k * 64 + c] = w2[i2];
  }
}

// -------- fused conv1 + conv2, one block per image --------
// LDS: img[48*72]=3456, c1[32][23][36]=26496 (pad 36 keeps rows 8B aligned),
//      w0[288], b0[32]  => 30272 floats = 121,088 B dynamic LDS
__global__ __launch_bounds__(256) void k_conv12(const float* __restrict__ gimg,
        const float* __restrict__ w0, const float* __restrict__ b0,
        const float* __restrict__ w1t, const float* __restrict__ b1,
        float* __restrict__ gout2) {
  extern __shared__ float lds[];
  float* simg = lds;            // 3456
  float* sc1  = lds + 3456;     // 26496
  float* sw0  = sc1 + 26496;    // 288
  float* sb0  = sw0 + 288;      // 32
  const int n = blockIdx.x, t = threadIdx.x;

  const float* gi = gimg + n * 3456;
  for (int k = t; k < 3456; k += 256) simg[k] = gi[k];
  for (int k = t; k < 288; k += 256) sw0[k] = w0[k];
  if (t < 32) sb0[t] = b0[t];
  __syncthreads();

  // conv1 -> LDS
  for (int idx = t; idx < 25760; idx += 256) {
    int oc = idx / 805, sp = idx - oc * 805;
    int oh = sp / 35, ow = sp - oh * 35;
    const float* ip = simg + (2 * oh) * 72 + 2 * ow;
    const float* wp = sw0 + oc * 9;
    float a = sb0[oc];
#pragma unroll
    for (int kh = 0; kh < 3; ++kh)
      a += ip[kh * 72 + 0] * wp[kh * 3 + 0] + ip[kh * 72 + 1] * wp[kh * 3 + 1]
         + ip[kh * 72 + 2] * wp[kh * 3 + 2];
    sc1[oc * 828 + oh * 36 + ow] = fmaxf(a, 0.f);
  }
  __syncthreads();

  // conv2: thread = (ocq, g); oc in {ocq+16m}, sp = q*16+g
  const int ocq = t & 15, g = t >> 4;
  float acc[12][4];
  int rowb[12];
  float bb[4];
#pragma unroll
  for (int m = 0; m < 4; ++m) bb[m] = b1[ocq + 16 * m];
#pragma unroll
  for (int q = 0; q < 12; ++q) {
    int sp = q * 16 + g; if (sp > 186) sp = 186;
    int oh = sp / 17, ow = sp - oh * 17;
    rowb[q] = (2 * oh) * 36 + 2 * ow;
#pragma unroll
    for (int m = 0; m < 4; ++m) acc[q][m] = bb[m];
  }
  for (int c = 0; c < 32; ++c) {
    float wr[4][9];
    const float* wp = w1t + c * 576;
#pragma unroll
    for (int k = 0; k < 9; ++k)
#pragma unroll
      for (int m = 0; m < 4; ++m) wr[m][k] = wp[k * 64 + ocq + 16 * m];
    const float* cb = sc1 + c * 828;
#pragma unroll
    for (int q = 0; q < 12; ++q) {
      const float* p = cb + rowb[q];
#pragma unroll
      for (int kh = 0; kh < 3; ++kh) {
        float x0 = p[kh * 36], x1 = p[kh * 36 + 1], x2 = p[kh * 36 + 2];
#pragma unroll
        for (int m = 0; m < 4; ++m)
          acc[q][m] += x0 * wr[m][kh * 3] + x1 * wr[m][kh * 3 + 1] + x2 * wr[m][kh * 3 + 2];
      }
    }
  }
  float* go = gout2 + n * 11968;
#pragma unroll
  for (int q = 0; q < 12; ++q) {
    int sp = q * 16 + g;
    if (sp < 187)
#pragma unroll
      for (int m = 0; m < 4; ++m)
        go[sp * 64 + ocq + 16 * m] = fmaxf(acc[q][m], 0.f);
  }
}

// -------- conv3 + concat, one block per image --------
// LDS: in2 [187][68]=12716, w2 [32][577]=18464 (577 stride -> conflict-free)
__global__ __launch_bounds__(256) void k_conv3(const float* __restrict__ gout2,
        const float* __restrict__ w2t, const float* __restrict__ b2,
        const float* __restrict__ grel, float* __restrict__ gx) {
  extern __shared__ float lds[];
  float* sin2 = lds;            // 12716
  float* sw2  = lds + 12716;    // 18464
  const int n = blockIdx.x, t = threadIdx.x;

  const float* gi = gout2 + n * 11968;
  for (int idx = t; idx < 11968; idx += 256) {
    int sp = idx >> 6, c = idx & 63;
    sin2[sp * 68 + c] = gi[idx];
  }
  for (int idx = t; idx < 18432; idx += 256) {
    int oc = idx / 576;
    sw2[oc * 577 + (idx - oc * 576)] = w2t[idx];
  }
  __syncthreads();

  const int oc = t & 15, g = t >> 4;   // oc handles {oc, oc+16}; sp = q*16+g
  float acc[3][2];
  int rowb[3];
#pragma unroll
  for (int q = 0; q < 3; ++q) {
    acc[q][0] = b2[oc]; acc[q][1] = b2[oc + 16];
    int sp = q * 16 + g; if (sp > 39) sp = 39;
    int oh = sp >> 3, ow = sp & 7;
    rowb[q] = ((2 * oh) * 17 + 2 * ow) * 68;
  }
  for (int c = 0; c < 64; ++c) {
    float wr0[9], wr1[9];
#pragma unroll
    for (int k = 0; k < 9; ++k) {
      wr0[k] = sw2[oc * 577 + k * 64 + c];
      wr1[k] = sw2[(oc + 16) * 577 + k * 64 + c];
    }
#pragma unroll
    for (int q = 0; q < 3; ++q) {
      const float* p = sin2 + rowb[q] + c;
#pragma unroll
      for (int kh = 0; kh < 3; ++kh) {
        float x0 = p[(kh * 17 + 0) * 68], x1 = p[(kh * 17 + 1) * 68], x2 = p[(kh * 17 + 2) * 68];
        acc[q][0] += x0 * wr0[3 * kh] + x1 * wr0[3 * kh + 1] + x2 * wr0[3 * kh + 2];
        acc[q][1] += x0 * wr1[3 * kh] + x1 * wr1[3 * kh + 1] + x2 * wr1[3 * kh + 2];
      }
    }
  }
  float* xo = gx + n * 1283;
#pragma unroll
  for (int q = 0; q < 3; ++q) {
    int sp = q * 16 + g;
    if (sp < 40) {
      xo[oc * 40 + sp]        = fmaxf(acc[q][0], 0.f);
      xo[(oc + 16) * 40 + sp] = fmaxf(acc[q][1], 0.f);
    }
  }
  if (t < 3) xo[1280 + t] = grel[n * 3 + t];
}

// -------- sensory synapse sums: 8 time-slots per block --------
__global__ __launch_bounds__(256) void k_sensory(const float* __restrict__ gx,
        const float* __restrict__ iw, const float* __restrict__ ib,
        const float* __restrict__ psig, const float* __restrict__ pmu,
        const float* __restrict__ pw, const float* __restrict__ pwe,
        float* __restrict__ wnum, float* __restrict__ wden) {
  __shared__ float xs[8 * 1283];
  const int t = threadIdx.x;
  const int bs0 = blockIdx.x * 8;
  for (int idx = t; idx < 8 * 1283; idx += 256) {
    int slot = idx / 1283, i = idx - slot * 1283;
    xs[idx] = gx[(bs0 + slot) * 1283 + i] * iw[i] + ib[i];
  }
  __syncthreads();
  const int w = t >> 6, l = t & 63;
  for (int jj = 0; jj < 12; ++jj) {
    int j = w * 12 + jj;
    const float* pa = psig + j * 1283;
    const float* pm = pmu + j * 1283;
    const float* pww = pw + j * 1283;
    const float* pe = pwe + j * 1283;
    float an[8], ad[8];
#pragma unroll
    for (int s2 = 0; s2 < 8; ++s2) { an[s2] = 0.f; ad[s2] = 0.f; }
    for (int i = l; i < 1283; i += 64) {
      float a = pa[i], m = pm[i], ww = pww[i], we = pe[i];
#pragma unroll
      for (int s2 = 0; s2 < 8; ++s2) {
        float sg = sigmoid_f((xs[s2 * 1283 + i] - m) * a);
        an[s2] += we * sg;
        ad[s2] += ww * sg;
      }
    }
#pragma unroll
    for (int off = 32; off; off >>= 1)
#pragma unroll
      for (int s2 = 0; s2 < 8; ++s2) {
        an[s2] += __shfl_xor(an[s2], off);
        ad[s2] += __shfl_xor(ad[s2], off);
      }
    if (l == 0) {
#pragma unroll
      for (int s2 = 0; s2 < 8; ++s2) {
        wnum[(bs0 + s2) * 48 + j] = an[s2];
        wden[(bs0 + s2) * 48 + j] = ad[s2];
      }
    }
  }
}

// -------- LTC scan: one block per batch, 48 posts x 8 pre-groups --------
__global__ __launch_bounds__(384) void k_scan(const float* __restrict__ gmu,
        const float* __restrict__ gsig, const float* __restrict__ wm,
        const float* __restrict__ wme, const float* __restrict__ wnum,
        const float* __restrict__ wden, const float* __restrict__ gleak,
        const float* __restrict__ vleak, const float* __restrict__ cm,
        const float* __restrict__ w_out, const float* __restrict__ b_out,
        const float* __restrict__ w_head, const float* __restrict__ b_head,
        float* __restrict__ out) {
  __shared__ float smu[48 * 49], ssg[48 * 49], swm[48 * 49], swe[48 * 49];
  __shared__ float vbuf[2][48];
  __shared__ float m4[4];
  const int t = threadIdx.x, b = blockIdx.x;
  for (int idx = t; idx < 2304; idx += 384) {
    int i = idx / 48, jx = idx - i * 48;
    int o = i * 49 + jx;
    smu[o] = gmu[idx]; ssg[o] = gsig[idx];
    swm[o] = wm[idx];  swe[o] = wme[idx];
  }
  if (t < 48) { vbuf[0][t] = 0.f; vbuf[1][t] = 0.f; }
  __syncthreads();

  const int j = t >> 3, g = t & 7;
  const float cmt = cm[j] * 6.f;
  const float gl = gleak[j];
  const float glv = gl * vleak[j];
  float psum = 0.f;
  const float* pn = wnum + b * 2304 + j;
  const float* pd = wden + b * 2304 + j;

  for (int s = 0; s < 48; ++s) {
    float wns = pn[s * 48], wds = pd[s * 48];
#pragma unroll 1
    for (int u = 0; u < 6; ++u) {
      int cur = u & 1;
      float an = 0.f, ad = 0.f;
#pragma unroll
      for (int q = 0; q < 6; ++q) {
        int i = g * 6 + q;
        float vi = vbuf[cur][i];
        float sg = sigmoid_f((vi - smu[i * 49 + j]) * ssg[i * 49 + j]);
        an += swe[i * 49 + j] * sg;
        ad += swm[i * 49 + j] * sg;
      }
      an += __shfl_xor(an, 1); ad += __shfl_xor(ad, 1);
      an += __shfl_xor(an, 2); ad += __shfl_xor(ad, 2);
      an += __shfl_xor(an, 4); ad += __shfl_xor(ad, 4);
      if (g == 0) {
        float vj = vbuf[cur][j];
        float num = cmt * vj + glv + an + wns;
        float den = cmt + gl + ad + wds + 1e-8f;
        vbuf[cur ^ 1][j] = num / den;
      }
      __syncthreads();
    }
    if (g == 0 && j < 4) psum += vbuf[0][j];
  }
  if (g == 0 && j < 4) m4[j] = psum * (1.f / 48.f) * w_out[j] + b_out[j];
  __syncthreads();
  if (t < 2) {
    float a = b_head[t];
#pragma unroll
    for (int jm = 0; jm < 4; ++jm) a += m4[jm] * w_head[jm * 2 + t];
    out[b * 2 + t] = tanhf(a);
  }
}

extern "C" void kernel_launch(void* const* d_in, const int* in_sizes, int n_in,
                              void* d_out, int out_size, void* d_ws, size_t ws_size,
                              hipStream_t stream) {
  const float* image   = (const float*)d_in[0];
  const float* rel     = (const float*)d_in[1];
  const float* w0      = (const float*)d_in[2];
  const float* b0      = (const float*)d_in[3];
  const float* w1      = (const float*)d_in[4];
  const float* b1      = (const float*)d_in[5];
  const float* w2      = (const float*)d_in[6];
  const float* b2      = (const float*)d_in[7];
  const float* iw      = (const float*)d_in[8];
  const float* ib      = (const float*)d_in[9];
  const float* gleak   = (const float*)d_in[10];
  const float* vleak   = (const float*)d_in[11];
  const float* cm      = (const float*)d_in[12];
  const float* sigma   = (const float*)d_in[13];
  const float* mu      = (const float*)d_in[14];
  const float* w_syn   = (const float*)d_in[15];
  const float* erev    = (const float*)d_in[16];
  const float* s_sigma = (const float*)d_in[17];
  const float* s_mu    = (const float*)d_in[18];
  const float* s_w     = (const float*)d_in[19];
  const float* s_erev  = (const float*)d_in[20];
  const float* w_out   = (const float*)d_in[21];
  const float* b_out   = (const float*)d_in[22];
  const float* w_head  = (const float*)d_in[23];
  const float* b_head  = (const float*)d_in[24];
  const int* syn_mask  = (const int*)d_in[25];
  const int* sens_mask = (const int*)d_in[26];
  float* ws  = (float*)d_ws;
  float* out = (float*)d_out;

  hipFuncSetAttribute((const void*)k_conv12, hipFuncAttributeMaxDynamicSharedMemorySize, 131072);
  hipFuncSetAttribute((const void*)k_conv3,  hipFuncAttributeMaxDynamicSharedMemorySize, 131072);

  k_pre_sensory<<<(1283 * 48 + 255) / 256, 256, 0, stream>>>(
      s_sigma, s_mu, s_w, s_erev, sens_mask,
      ws + O_SSIG, ws + O_SMU, ws + O_SW, ws + O_SWE);
  k_pre_rec<<<9, 256, 0, stream>>>(w_syn, erev, syn_mask, ws + O_WM, ws + O_WME);
  k_pre_w<<<144, 256, 0, stream>>>(w1, w2, ws + O_W1T, ws + O_W2T);

  k_conv12<<<1536, 256, 121088, stream>>>(image, w0, b0, ws + O_W1T, b1, ws + O_OUT2);
  k_conv3<<<1536, 256, 124720, stream>>>(ws + O_OUT2, ws + O_W2T, b2, rel, ws + O_X);

  k_sensory<<<192, 256, 0, stream>>>(ws + O_X, iw, ib,
      ws + O_SSIG, ws + O_SMU, ws + O_SW, ws + O_SWE, ws + O_WNUM, ws + O_WDEN);

  k_scan<<<32, 384, 0, stream>>>(mu, sigma, ws + O_WM, ws + O_WME,
      ws + O_WNUM, ws + O_WDEN, gleak, vleak, cm,
      w_out, b_out, w_head, b_head, out);
}